// Round 1
// baseline (542.418 us; speedup 1.0000x reference)
//
#include <hip/hip_runtime.h>
#include <math.h>

#define S      256     // N_SAMPLES (reference constant)
#define GN     128     // GRID
#define FEAT   64
#define HID    128
#define RHID   64

__global__ __launch_bounds__(256, 2)
void nerf_fused(const float* __restrict__ rays_o,
                const float* __restrict__ rays_d,
                const float* __restrict__ grid,
                const float* __restrict__ f_w1,
                const float* __restrict__ f_b1,
                const float* __restrict__ f_w2,
                const float* __restrict__ f_b2,
                const float* __restrict__ s_w,
                const float* __restrict__ s_b,
                const float* __restrict__ r_w1,
                const float* __restrict__ r_b1,
                const float* __restrict__ r_w2,
                const float* __restrict__ r_b2,
                float* __restrict__ out)
{
    __shared__ float sW1[3 * HID];            // 384
    __shared__ float sB1[HID];                // 128
    __shared__ float sW2[HID * FEAT];         // 8192
    __shared__ float sB2[FEAT];               // 64
    __shared__ float sSW[FEAT];               // 64
    __shared__ float sRW1[(FEAT + 3) * RHID]; // 4288
    __shared__ float sRB1[RHID];              // 64
    __shared__ float sRW2[RHID * 3];          // 192
    __shared__ float sScan[S];                // 256
    __shared__ float sPart[4][3];             // per-wave partial rgb

    const int tid = threadIdx.x;
    const int ray = blockIdx.x;

    // ---- stage weights into LDS (coalesced, once per block) ----
    for (int i = tid; i < 3 * HID; i += 256)          sW1[i]  = f_w1[i];
    for (int i = tid; i < HID; i += 256)              sB1[i]  = f_b1[i];
    for (int i = tid; i < HID * FEAT; i += 256)       sW2[i]  = f_w2[i];
    for (int i = tid; i < FEAT; i += 256)           { sB2[i]  = f_b2[i]; sSW[i] = s_w[i]; }
    for (int i = tid; i < (FEAT + 3) * RHID; i += 256) sRW1[i] = r_w1[i];
    for (int i = tid; i < RHID; i += 256)             sRB1[i] = r_b1[i];
    for (int i = tid; i < RHID * 3; i += 256)         sRW2[i] = r_w2[i];

    const float sb   = s_b[0];
    const float rb20 = r_b2[0], rb21 = r_b2[1], rb22 = r_b2[2];

    __syncthreads();

    // ---- unbounded stepping: t and dist for this sample ----
    const float stop = 1.0f - 1.0f / (float)(S + 2);
    const float step = stop / (float)S;
    float u0 = (float)tid * step;
    float u1 = (float)(tid + 1) * step;
    float t   = (u0 < 0.5f) ? 2.0f * u0 : 1.0f / (2.0f - 2.0f * u0);
    float tn  = (u1 < 0.5f) ? 2.0f * u1 : 1.0f / (2.0f - 2.0f * u1);
    float dist = tn - t;

    float ox = rays_o[ray * 3 + 0], oy = rays_o[ray * 3 + 1], oz = rays_o[ray * 3 + 2];
    float dx = rays_d[ray * 3 + 0], dy = rays_d[ray * 3 + 1], dz = rays_d[ray * 3 + 2];

    float px = ox + dx * t, py = oy + dy * t, pz = oz + dz * t;

    // ---- mip360 contraction, then /2 ----
    float nrm = sqrtf(px * px + py * py + pz * pz);
    float scale = (nrm <= 1.0f) ? 0.5f : (2.0f - 1.0f / nrm) / nrm * 0.5f;
    float cx = px * scale, cy = py * scale, cz = pz * scale;

    // ---- trilinear grid sample (x->W, y->H, z->D), zeros padding ----
    float ix = ((cx + 1.0f) * (float)GN - 1.0f) * 0.5f;
    float iy = ((cy + 1.0f) * (float)GN - 1.0f) * 0.5f;
    float iz = ((cz + 1.0f) * (float)GN - 1.0f) * 0.5f;
    float fx0 = floorf(ix), fy0 = floorf(iy), fz0 = floorf(iz);
    float fx = ix - fx0, fy = iy - fy0, fz = iz - fz0;
    int x0 = (int)fx0, y0 = (int)fy0, z0 = (int)fz0;

    float occ = 0.0f;
    #pragma unroll
    for (int dzc = 0; dzc < 2; ++dzc)
    #pragma unroll
    for (int dyc = 0; dyc < 2; ++dyc)
    #pragma unroll
    for (int dxc = 0; dxc < 2; ++dxc) {
        int xc = x0 + dxc, yc = y0 + dyc, zc = z0 + dzc;
        float w = (dxc ? fx : 1.0f - fx) * (dyc ? fy : 1.0f - fy) * (dzc ? fz : 1.0f - fz);
        if (xc >= 0 && xc < GN && yc >= 0 && yc < GN && zc >= 0 && zc < GN)
            occ += w * grid[(zc * GN + yc) * GN + xc];
    }
    bool mask = occ > 0.01f;

    // ---- feature MLP: relu(pos @ W1 + b1) @ W2 + b2 ----
    float feat[FEAT];
    #pragma unroll
    for (int j = 0; j < FEAT; ++j) feat[j] = sB2[j];
    for (int k = 0; k < HID; ++k) {
        float h = sB1[k] + cx * sW1[k] + cy * sW1[HID + k] + cz * sW1[2 * HID + k];
        h = fmaxf(h, 0.0f);
        const float4* w4 = (const float4*)(&sW2[k * FEAT]);
        #pragma unroll
        for (int j = 0; j < FEAT / 4; ++j) {
            float4 w = w4[j];
            feat[4 * j + 0] += h * w.x;
            feat[4 * j + 1] += h * w.y;
            feat[4 * j + 2] += h * w.z;
            feat[4 * j + 3] += h * w.w;
        }
    }
    if (!mask) {
        #pragma unroll
        for (int j = 0; j < FEAT; ++j) feat[j] = 0.0f;
    }

    // ---- sigma head: softplus(feat @ s_w + s_b), masked ----
    float sa = sb;
    #pragma unroll
    for (int j = 0; j < FEAT; ++j) sa += feat[j] * sSW[j];
    float sigma = mask ? (fmaxf(sa, 0.0f) + __logf(1.0f + __expf(-fabsf(sa)))) : 0.0f;

    float a = -sigma * dist;

    // ---- exclusive prefix sum of a across the ray (Hillis-Steele in LDS) ----
    sScan[tid] = a;
    __syncthreads();
    #pragma unroll
    for (int off = 1; off < S; off <<= 1) {
        float v = (tid >= off) ? sScan[tid - off] : 0.0f;
        __syncthreads();
        sScan[tid] += v;
        __syncthreads();
    }
    float cum = (tid == 0) ? 0.0f : sScan[tid - 1];
    float trans  = __expf(cum);
    float weight = trans * (1.0f - __expf(a));
    bool mask2 = mask && (trans > 1e-4f);

    // ---- rgb MLP: relu([feat, dir] @ r_w1 + r_b1) @ r_w2 + r_b2 -> sigmoid ----
    float r = 0.0f, g = 0.0f, b = 0.0f;
    if (mask2) {
        float h[RHID];
        #pragma unroll
        for (int j = 0; j < RHID; ++j) h[j] = sRB1[j];
        #pragma unroll
        for (int k = 0; k < FEAT; ++k) {
            float f = feat[k];
            const float4* w4 = (const float4*)(&sRW1[k * RHID]);
            #pragma unroll
            for (int j = 0; j < RHID / 4; ++j) {
                float4 w = w4[j];
                h[4 * j + 0] += f * w.x;
                h[4 * j + 1] += f * w.y;
                h[4 * j + 2] += f * w.z;
                h[4 * j + 3] += f * w.w;
            }
        }
        {
            const float4* wx = (const float4*)(&sRW1[(FEAT + 0) * RHID]);
            const float4* wy = (const float4*)(&sRW1[(FEAT + 1) * RHID]);
            const float4* wz = (const float4*)(&sRW1[(FEAT + 2) * RHID]);
            #pragma unroll
            for (int j = 0; j < RHID / 4; ++j) {
                float4 aw = wx[j], bw = wy[j], cw = wz[j];
                h[4 * j + 0] += dx * aw.x + dy * bw.x + dz * cw.x;
                h[4 * j + 1] += dx * aw.y + dy * bw.y + dz * cw.y;
                h[4 * j + 2] += dx * aw.z + dy * bw.z + dz * cw.z;
                h[4 * j + 3] += dx * aw.w + dy * bw.w + dz * cw.w;
            }
        }
        float o0 = rb20, o1 = rb21, o2 = rb22;
        #pragma unroll
        for (int k = 0; k < RHID; ++k) {
            float hk = fmaxf(h[k], 0.0f);
            o0 += hk * sRW2[k * 3 + 0];
            o1 += hk * sRW2[k * 3 + 1];
            o2 += hk * sRW2[k * 3 + 2];
        }
        r = weight / (1.0f + __expf(-o0));
        g = weight / (1.0f + __expf(-o1));
        b = weight / (1.0f + __expf(-o2));
    }

    // ---- reduce rgb over 256 samples: wave shuffle + cross-wave LDS ----
    #pragma unroll
    for (int off = 32; off > 0; off >>= 1) {
        r += __shfl_down(r, off);
        g += __shfl_down(g, off);
        b += __shfl_down(b, off);
    }
    int wid = tid >> 6, lane = tid & 63;
    if (lane == 0) { sPart[wid][0] = r; sPart[wid][1] = g; sPart[wid][2] = b; }
    __syncthreads();
    if (tid == 0) {
        out[ray * 3 + 0] = sPart[0][0] + sPart[1][0] + sPart[2][0] + sPart[3][0];
        out[ray * 3 + 1] = sPart[0][1] + sPart[1][1] + sPart[2][1] + sPart[3][1];
        out[ray * 3 + 2] = sPart[0][2] + sPart[1][2] + sPart[2][2] + sPart[3][2];
    }
}

extern "C" void kernel_launch(void* const* d_in, const int* in_sizes, int n_in,
                              void* d_out, int out_size, void* d_ws, size_t ws_size,
                              hipStream_t stream) {
    const int n_rays = in_sizes[0] / 3;   // 4096
    // n_samples (d_in[13]) is fixed at 256 by the reference harness; S is compile-time.
    nerf_fused<<<n_rays, 256, 0, stream>>>(
        (const float*)d_in[0],  (const float*)d_in[1],  (const float*)d_in[2],
        (const float*)d_in[3],  (const float*)d_in[4],  (const float*)d_in[5],
        (const float*)d_in[6],  (const float*)d_in[7],  (const float*)d_in[8],
        (const float*)d_in[9],  (const float*)d_in[10], (const float*)d_in[11],
        (const float*)d_in[12], (float*)d_out);
}

// Round 2
// 469.086 us; speedup vs baseline: 1.1563x; 1.1563x over previous
//
#include <hip/hip_runtime.h>
#include <math.h>

#define S      256     // N_SAMPLES
#define GN     128     // GRID
#define FEAT   64
#define HID    128
#define RHID   64

__global__ __launch_bounds__(256, 4)
void nerf_fused(const float* __restrict__ rays_o,
                const float* __restrict__ rays_d,
                const float* __restrict__ grid,
                const float* __restrict__ f_w1,
                const float* __restrict__ f_b1,
                const float* __restrict__ f_w2,
                const float* __restrict__ f_b2,
                const float* __restrict__ s_w,
                const float* __restrict__ s_b,
                const float* __restrict__ r_w1,
                const float* __restrict__ r_b1,
                const float* __restrict__ r_w2,
                const float* __restrict__ r_b2,
                float* __restrict__ out)
{
    __shared__ float sWaveSum[4];
    __shared__ float sPart[4][3];

    const int tid  = threadIdx.x;
    const int ray  = blockIdx.x;
    const int lane = tid & 63;
    const int wid  = tid >> 6;

    // ---- unbounded stepping ----
    const float stop = 1.0f - 1.0f / (float)(S + 2);
    const float step = stop / (float)S;
    float u0 = (float)tid * step;
    float u1 = (float)(tid + 1) * step;
    float t    = (u0 < 0.5f) ? 2.0f * u0 : 1.0f / (2.0f - 2.0f * u0);
    float tn   = (u1 < 0.5f) ? 2.0f * u1 : 1.0f / (2.0f - 2.0f * u1);
    float dist = tn - t;

    // block-uniform ray origin/dir -> scalar loads
    float ox = rays_o[ray * 3 + 0], oy = rays_o[ray * 3 + 1], oz = rays_o[ray * 3 + 2];
    float dx = rays_d[ray * 3 + 0], dy = rays_d[ray * 3 + 1], dz = rays_d[ray * 3 + 2];

    float px = ox + dx * t, py = oy + dy * t, pz = oz + dz * t;

    // ---- mip360 contraction (incl. final /2) ----
    float nrm = sqrtf(px * px + py * py + pz * pz);
    float scale = (nrm <= 1.0f) ? 0.5f : (2.0f - 1.0f / nrm) / nrm * 0.5f;
    float cx = px * scale, cy = py * scale, cz = pz * scale;

    // ---- trilinear grid sample, zeros padding ----
    float ix = ((cx + 1.0f) * (float)GN - 1.0f) * 0.5f;
    float iy = ((cy + 1.0f) * (float)GN - 1.0f) * 0.5f;
    float iz = ((cz + 1.0f) * (float)GN - 1.0f) * 0.5f;
    float fx0 = floorf(ix), fy0 = floorf(iy), fz0 = floorf(iz);
    float fx = ix - fx0, fy = iy - fy0, fz = iz - fz0;
    int x0 = (int)fx0, y0 = (int)fy0, z0 = (int)fz0;

    float occ = 0.0f;
    #pragma unroll
    for (int dzc = 0; dzc < 2; ++dzc)
    #pragma unroll
    for (int dyc = 0; dyc < 2; ++dyc)
    #pragma unroll
    for (int dxc = 0; dxc < 2; ++dxc) {
        int xc = x0 + dxc, yc = y0 + dyc, zc = z0 + dzc;
        float w = (dxc ? fx : 1.0f - fx) * (dyc ? fy : 1.0f - fy) * (dzc ? fz : 1.0f - fz);
        if (xc >= 0 && xc < GN && yc >= 0 && yc < GN && zc >= 0 && zc < GN)
            occ += w * grid[(zc * GN + yc) * GN + xc];
    }
    bool mask = occ > 0.01f;

    // ---- feature MLP: relu(pos @ W1 + b1) @ W2 + b2 ----
    // Weights read with wave-uniform indices straight from global -> s_load,
    // SGPR operand in v_fmac; no LDS pipe traffic.
    float feat[FEAT];
    #pragma unroll
    for (int j = 0; j < FEAT; ++j) feat[j] = f_b2[j];
    for (int k = 0; k < HID; ++k) {
        float h = f_b1[k] + cx * f_w1[k] + cy * f_w1[HID + k] + cz * f_w1[2 * HID + k];
        h = fmaxf(h, 0.0f);
        const float* __restrict__ w = &f_w2[k * FEAT];
        #pragma unroll
        for (int j = 0; j < FEAT; ++j) feat[j] += h * w[j];
    }
    if (!mask) {
        #pragma unroll
        for (int j = 0; j < FEAT; ++j) feat[j] = 0.0f;
    }

    // ---- sigma head ----
    float sa = s_b[0];
    #pragma unroll
    for (int j = 0; j < FEAT; ++j) sa += feat[j] * s_w[j];
    float sigma = mask ? (fmaxf(sa, 0.0f) + __logf(1.0f + __expf(-fabsf(sa)))) : 0.0f;
    float a = -sigma * dist;

    // ---- exclusive scan of a over the 256 samples (shuffle scan, 1 barrier) ----
    float v = a;
    #pragma unroll
    for (int off = 1; off < 64; off <<= 1) {
        float u = __shfl_up(v, off);
        if (lane >= off) v += u;
    }
    if (lane == 63) sWaveSum[wid] = v;
    __syncthreads();
    float base = 0.0f;
    #pragma unroll
    for (int w = 0; w < 4; ++w) base += (w < wid) ? sWaveSum[w] : 0.0f;
    float excl = __shfl_up(v, 1);            // exclusive within wave
    if (lane == 0) excl = 0.0f;
    float cum = base + excl;

    float trans  = __expf(cum);
    float weight = trans * (1.0f - __expf(a));
    bool mask2 = mask && (trans > 1e-4f);

    // ---- rgb MLP (chunked hidden: 2 x 32 to cap VGPR pressure) ----
    float r = 0.0f, g = 0.0f, b = 0.0f;
    if (mask2) {
        float o0 = r_b2[0], o1 = r_b2[1], o2 = r_b2[2];
        for (int c = 0; c < 2; ++c) {
            const int j0 = c * 32;
            float h[32];
            #pragma unroll
            for (int j = 0; j < 32; ++j) h[j] = r_b1[j0 + j];
            #pragma unroll
            for (int k = 0; k < FEAT; ++k) {
                float f = feat[k];
                const float* __restrict__ w = &r_w1[k * RHID + j0];
                #pragma unroll
                for (int j = 0; j < 32; ++j) h[j] += f * w[j];
            }
            {
                const float* __restrict__ wx = &r_w1[(FEAT + 0) * RHID + j0];
                const float* __restrict__ wy = &r_w1[(FEAT + 1) * RHID + j0];
                const float* __restrict__ wz = &r_w1[(FEAT + 2) * RHID + j0];
                #pragma unroll
                for (int j = 0; j < 32; ++j)
                    h[j] += dx * wx[j] + dy * wy[j] + dz * wz[j];
            }
            #pragma unroll
            for (int j = 0; j < 32; ++j) {
                float hk = fmaxf(h[j], 0.0f);
                int jj = j0 + j;
                o0 += hk * r_w2[jj * 3 + 0];
                o1 += hk * r_w2[jj * 3 + 1];
                o2 += hk * r_w2[jj * 3 + 2];
            }
        }
        r = weight / (1.0f + __expf(-o0));
        g = weight / (1.0f + __expf(-o1));
        b = weight / (1.0f + __expf(-o2));
    }

    // ---- reduce rgb over samples ----
    #pragma unroll
    for (int off = 32; off > 0; off >>= 1) {
        r += __shfl_down(r, off);
        g += __shfl_down(g, off);
        b += __shfl_down(b, off);
    }
    if (lane == 0) { sPart[wid][0] = r; sPart[wid][1] = g; sPart[wid][2] = b; }
    __syncthreads();
    if (tid == 0) {
        out[ray * 3 + 0] = sPart[0][0] + sPart[1][0] + sPart[2][0] + sPart[3][0];
        out[ray * 3 + 1] = sPart[0][1] + sPart[1][1] + sPart[2][1] + sPart[3][1];
        out[ray * 3 + 2] = sPart[0][2] + sPart[1][2] + sPart[2][2] + sPart[3][2];
    }
}

extern "C" void kernel_launch(void* const* d_in, const int* in_sizes, int n_in,
                              void* d_out, int out_size, void* d_ws, size_t ws_size,
                              hipStream_t stream) {
    const int n_rays = in_sizes[0] / 3;   // 4096
    nerf_fused<<<n_rays, 256, 0, stream>>>(
        (const float*)d_in[0],  (const float*)d_in[1],  (const float*)d_in[2],
        (const float*)d_in[3],  (const float*)d_in[4],  (const float*)d_in[5],
        (const float*)d_in[6],  (const float*)d_in[7],  (const float*)d_in[8],
        (const float*)d_in[9],  (const float*)d_in[10], (const float*)d_in[11],
        (const float*)d_in[12], (float*)d_out);
}

// Round 3
// 254.598 us; speedup vs baseline: 2.1305x; 1.8425x over previous
//
#include <hip/hip_runtime.h>
#include <math.h>
#include <stdint.h>

#define S    256
#define GN   128

typedef __attribute__((ext_vector_type(8))) short  short8;   // 8 bf16 (4 VGPRs)
typedef __attribute__((ext_vector_type(4))) float  floatx4;  // MFMA C/D

__device__ __forceinline__ unsigned short bf16_rtne(float f) {
    uint32_t u = __builtin_bit_cast(uint32_t, f);
    uint32_t r = (u + 0x7fffu + ((u >> 16) & 1u)) >> 16;
    return (unsigned short)r;
}
__device__ __forceinline__ float bf16_to_f(unsigned short s) {
    uint32_t u = ((uint32_t)s) << 16;
    return __builtin_bit_cast(float, u);
}

// MFMA fragment layout (verified, guide §3):
//   A: A[m = lane&15][k = (lane>>4)*8 + j]   (short8)
//   B: B[k = (lane>>4)*8 + j][n = lane&15]   (short8)
//   C/D: col n = lane&15, row m_local = (lane>>4)*4 + reg
__global__ __launch_bounds__(256, 3)
void nerf_mfma(const float* __restrict__ rays_o,
               const float* __restrict__ rays_d,
               const float* __restrict__ grid,
               const float* __restrict__ f_w1,
               const float* __restrict__ f_b1,
               const float* __restrict__ f_w2,
               const float* __restrict__ f_b2,
               const float* __restrict__ s_w,
               const float* __restrict__ s_b,
               const float* __restrict__ r_w1,
               const float* __restrict__ r_b1,
               const float* __restrict__ r_w2,
               const float* __restrict__ r_b2,
               float* __restrict__ out)
{
    // One buffer, three lives: A1 staging (uint32 [256][33], hi|lo packed)
    // -> feat bf16 (ushort [256][66]) -> rgb-h bf16 (ushort [256][66]).
    // 256*33*4 == 256*66*2 == 33792 bytes. feat/h rows are wave-private.
    __shared__ union {
        uint32_t       a1[256 * 33];
        unsigned short fh[256 * 66];
    } uLds;
    __shared__ float aLds[S];
    __shared__ float maskLds[S];
    __shared__ float distLds[S];
    __shared__ float w2Lds[192];          // r_w2 staged for broadcast reads
    __shared__ float sWaveSum[4];
    __shared__ float sPart[4][3];

    const int tid   = threadIdx.x;
    const int ray   = blockIdx.x;
    const int lane  = tid & 63;
    const int wv    = tid >> 6;           // wave 0..3, owns samples [64wv, 64wv+64)
    const int q     = lane >> 4;
    const int c     = lane & 15;
    const int mbase = wv * 64;

    if (tid < 192) w2Lds[tid] = r_w2[tid];

    // ---------------- Phase A: per-sample geometry + grid sample -------------
    const float stop = 1.0f - 1.0f / (float)(S + 2);
    const float step = stop / (float)S;
    float u0 = (float)tid * step;
    float u1 = (float)(tid + 1) * step;
    float t    = (u0 < 0.5f) ? 2.0f * u0 : 1.0f / (2.0f - 2.0f * u0);
    float tn_  = (u1 < 0.5f) ? 2.0f * u1 : 1.0f / (2.0f - 2.0f * u1);
    float dist = tn_ - t;

    float ox = rays_o[ray * 3 + 0], oy = rays_o[ray * 3 + 1], oz = rays_o[ray * 3 + 2];
    float dxv = rays_d[ray * 3 + 0], dyv = rays_d[ray * 3 + 1], dzv = rays_d[ray * 3 + 2];

    float px = ox + dxv * t, py = oy + dyv * t, pz = oz + dzv * t;
    float nrm = sqrtf(px * px + py * py + pz * pz);
    float scale = (nrm <= 1.0f) ? 0.5f : (2.0f - 1.0f / nrm) / nrm * 0.5f;
    float cx = px * scale, cy = py * scale, cz = pz * scale;

    float ix = ((cx + 1.0f) * (float)GN - 1.0f) * 0.5f;
    float iy = ((cy + 1.0f) * (float)GN - 1.0f) * 0.5f;
    float iz = ((cz + 1.0f) * (float)GN - 1.0f) * 0.5f;
    float fx0 = floorf(ix), fy0 = floorf(iy), fz0 = floorf(iz);
    float fx = ix - fx0, fy = iy - fy0, fz = iz - fz0;
    int x0 = (int)fx0, y0 = (int)fy0, z0 = (int)fz0;

    float occ = 0.0f;
    #pragma unroll
    for (int dzc = 0; dzc < 2; ++dzc)
    #pragma unroll
    for (int dyc = 0; dyc < 2; ++dyc)
    #pragma unroll
    for (int dxc = 0; dxc < 2; ++dxc) {
        int xc = x0 + dxc, yc = y0 + dyc, zc = z0 + dzc;
        float w = (dxc ? fx : 1.0f - fx) * (dyc ? fy : 1.0f - fy) * (dzc ? fz : 1.0f - fz);
        if (xc >= 0 && xc < GN && yc >= 0 && yc < GN && zc >= 0 && zc < GN)
            occ += w * grid[(zc * GN + yc) * GN + xc];
    }
    bool maskA = occ > 0.01f;
    maskLds[tid] = maskA ? 1.0f : 0.0f;
    distLds[tid] = dist;

    // ---------------- Phase B: feat GEMM (M=256,K=128,N=64), 3-term bf16 -----
    floatx4 facc[4][4];
    {
        float b2v[4];
        #pragma unroll
        for (int tn = 0; tn < 4; ++tn) b2v[tn] = f_b2[tn * 16 + c];
        #pragma unroll
        for (int tm = 0; tm < 4; ++tm)
            #pragma unroll
            for (int tn = 0; tn < 4; ++tn) {
                floatx4 v; v[0] = b2v[tn]; v[1] = b2v[tn]; v[2] = b2v[tn]; v[3] = b2v[tn];
                facc[tm][tn] = v;
            }
    }

    for (int kc = 0; kc < 4; ++kc) {
        const int j0 = kc * 32;
        // layer-1 (K=3) on VALU, thread = sample; hi/lo bf16 packed into LDS
        #pragma unroll
        for (int jj = 0; jj < 32; ++jj) {
            int j = j0 + jj;
            float h = f_b1[j] + cx * f_w1[j] + cy * f_w1[128 + j] + cz * f_w1[256 + j];
            h = fmaxf(h, 0.0f);
            unsigned short hi = bf16_rtne(h);
            unsigned short lo = bf16_rtne(h - bf16_to_f(hi));
            uLds.a1[tid * 33 + jj] = ((uint32_t)hi << 16) | (uint32_t)lo;
        }
        __syncthreads();

        // B frags (W2 block-uniform from global, L2-hot), hi+lo
        short8 bhi[4], blo[4];
        #pragma unroll
        for (int tn = 0; tn < 4; ++tn) {
            int n = tn * 16 + c;
            const float* bp = f_w2 + (j0 + q * 8) * 64 + n;
            #pragma unroll
            for (int j = 0; j < 8; ++j) {
                float w = bp[j * 64];
                unsigned short h16 = bf16_rtne(w);
                bhi[tn][j] = (short)h16;
                blo[tn][j] = (short)bf16_rtne(w - bf16_to_f(h16));
            }
        }
        // A frags + MFMA (3-term: AhBh + AlBh + AhBl)
        #pragma unroll
        for (int tm = 0; tm < 4; ++tm) {
            int m = mbase + tm * 16 + c;
            const uint32_t* ap = &uLds.a1[m * 33 + q * 8];
            short8 Ah, Al;
            #pragma unroll
            for (int j = 0; j < 8; ++j) {
                uint32_t pw = ap[j];
                Ah[j] = (short)(pw >> 16);
                Al[j] = (short)(pw & 0xffffu);
            }
            #pragma unroll
            for (int tn = 0; tn < 4; ++tn) {
                facc[tm][tn] = __builtin_amdgcn_mfma_f32_16x16x32_bf16(Ah, bhi[tn], facc[tm][tn], 0, 0, 0);
                facc[tm][tn] = __builtin_amdgcn_mfma_f32_16x16x32_bf16(Al, bhi[tn], facc[tm][tn], 0, 0, 0);
                facc[tm][tn] = __builtin_amdgcn_mfma_f32_16x16x32_bf16(Ah, blo[tn], facc[tm][tn], 0, 0, 0);
            }
        }
        __syncthreads();
    }

    // ---------------- Phase C: feat -> LDS bf16; sigma from fp32 acc ---------
    #pragma unroll
    for (int tm = 0; tm < 4; ++tm)
        #pragma unroll
        for (int tn = 0; tn < 4; ++tn)
            #pragma unroll
            for (int reg = 0; reg < 4; ++reg) {
                int m = mbase + tm * 16 + q * 4 + reg;
                int n = tn * 16 + c;
                uLds.fh[m * 66 + n] = bf16_rtne(facc[tm][tn][reg]);
            }

    {
        float swv[4];
        #pragma unroll
        for (int tn = 0; tn < 4; ++tn) swv[tn] = s_w[tn * 16 + c];
        float sbv = s_b[0];
        float p[16];
        #pragma unroll
        for (int tm = 0; tm < 4; ++tm)
            #pragma unroll
            for (int reg = 0; reg < 4; ++reg)
                p[tm * 4 + reg] = facc[tm][0][reg] * swv[0] + facc[tm][1][reg] * swv[1]
                                + facc[tm][2][reg] * swv[2] + facc[tm][3][reg] * swv[3];
        #pragma unroll
        for (int d = 1; d < 16; d <<= 1) {
            #pragma unroll
            for (int i = 0; i < 16; ++i) p[i] += __shfl_xor(p[i], d);
        }
        if (c == 0) {
            #pragma unroll
            for (int tm = 0; tm < 4; ++tm)
                #pragma unroll
                for (int reg = 0; reg < 4; ++reg) {
                    int m = mbase + tm * 16 + q * 4 + reg;
                    float sa = p[tm * 4 + reg] + sbv;
                    float sg = (maskLds[m] > 0.5f)
                             ? (fmaxf(sa, 0.0f) + __logf(1.0f + __expf(-fabsf(sa)))) : 0.0f;
                    aLds[m] = -sg * distLds[m];
                }
        }
    }
    __syncthreads();

    // ---------------- transmittance scan (thread = sample) -------------------
    float av = aLds[tid];
    float v = av;
    #pragma unroll
    for (int off = 1; off < 64; off <<= 1) {
        float u2 = __shfl_up(v, off);
        if (lane >= off) v += u2;
    }
    if (lane == 63) sWaveSum[wv] = v;
    __syncthreads();
    float basev = 0.0f;
    #pragma unroll
    for (int w = 0; w < 4; ++w) basev += (w < wv) ? sWaveSum[w] : 0.0f;
    float excl = __shfl_up(v, 1);
    if (lane == 0) excl = 0.0f;
    float cum    = basev + excl;
    float trans  = __expf(cum);
    float weight = trans * (1.0f - __expf(av));
    bool  mask2  = maskA && (trans > 1e-4f);

    // ---------------- Phase D: rgb-hidden GEMM (K=64,N=64), 1-term bf16 ------
    float hd[4];
    #pragma unroll
    for (int tn = 0; tn < 4; ++tn) {
        int n = tn * 16 + c;
        hd[tn] = r_b1[n] + dxv * r_w1[64 * 64 + n] + dyv * r_w1[65 * 64 + n] + dzv * r_w1[66 * 64 + n];
    }

    short8 afr[4][2];
    #pragma unroll
    for (int tm = 0; tm < 4; ++tm)
        #pragma unroll
        for (int ks = 0; ks < 2; ++ks) {
            int m = mbase + tm * 16 + c;
            const uint32_t* ap2 = (const uint32_t*)&uLds.fh[m * 66 + ks * 32 + q * 8];
            #pragma unroll
            for (int tt = 0; tt < 4; ++tt) {
                uint32_t pw = ap2[tt];
                afr[tm][ks][2 * tt]     = (short)(pw & 0xffffu);
                afr[tm][ks][2 * tt + 1] = (short)(pw >> 16);
            }
        }

    floatx4 hacc[4][4];
    #pragma unroll
    for (int tm = 0; tm < 4; ++tm)
        #pragma unroll
        for (int tn = 0; tn < 4; ++tn) {
            floatx4 z; z[0] = 0.0f; z[1] = 0.0f; z[2] = 0.0f; z[3] = 0.0f;
            hacc[tm][tn] = z;
        }
    #pragma unroll
    for (int ks = 0; ks < 2; ++ks) {
        short8 rb[4];
        #pragma unroll
        for (int tn = 0; tn < 4; ++tn) {
            int n = tn * 16 + c;
            const float* bp = r_w1 + (ks * 32 + q * 8) * 64 + n;
            #pragma unroll
            for (int j = 0; j < 8; ++j) rb[tn][j] = (short)bf16_rtne(bp[j * 64]);
        }
        #pragma unroll
        for (int tm = 0; tm < 4; ++tm)
            #pragma unroll
            for (int tn = 0; tn < 4; ++tn)
                hacc[tm][tn] = __builtin_amdgcn_mfma_f32_16x16x32_bf16(afr[tm][ks], rb[tn], hacc[tm][tn], 0, 0, 0);
    }
    // epilogue: + (b1 + dirs part), relu, store bf16 (wave-private rows)
    #pragma unroll
    for (int tm = 0; tm < 4; ++tm)
        #pragma unroll
        for (int tn = 0; tn < 4; ++tn)
            #pragma unroll
            for (int reg = 0; reg < 4; ++reg) {
                int m = mbase + tm * 16 + q * 4 + reg;
                int n = tn * 16 + c;
                float hv = fmaxf(hacc[tm][tn][reg] + hd[tn], 0.0f);
                uLds.fh[m * 66 + n] = bf16_rtne(hv);
            }

    // ---------------- Phase E: final 64->3 layer (thread = sample) -----------
    float o0 = r_b2[0], o1 = r_b2[1], o2 = r_b2[2];
    const uint32_t* hp = (const uint32_t*)&uLds.fh[tid * 66];
    #pragma unroll
    for (int tt = 0; tt < 32; ++tt) {
        uint32_t pw = hp[tt];
        float h0 = bf16_to_f((unsigned short)(pw & 0xffffu));
        float h1 = bf16_to_f((unsigned short)(pw >> 16));
        int k0 = 2 * tt, k1 = 2 * tt + 1;
        o0 += h0 * w2Lds[k0 * 3 + 0] + h1 * w2Lds[k1 * 3 + 0];
        o1 += h0 * w2Lds[k0 * 3 + 1] + h1 * w2Lds[k1 * 3 + 1];
        o2 += h0 * w2Lds[k0 * 3 + 2] + h1 * w2Lds[k1 * 3 + 2];
    }
    float r = 0.0f, g = 0.0f, b = 0.0f;
    if (mask2) {
        r = weight / (1.0f + __expf(-o0));
        g = weight / (1.0f + __expf(-o1));
        b = weight / (1.0f + __expf(-o2));
    }

    #pragma unroll
    for (int off = 32; off > 0; off >>= 1) {
        r += __shfl_down(r, off);
        g += __shfl_down(g, off);
        b += __shfl_down(b, off);
    }
    if (lane == 0) { sPart[wv][0] = r; sPart[wv][1] = g; sPart[wv][2] = b; }
    __syncthreads();
    if (tid == 0) {
        out[ray * 3 + 0] = sPart[0][0] + sPart[1][0] + sPart[2][0] + sPart[3][0];
        out[ray * 3 + 1] = sPart[0][1] + sPart[1][1] + sPart[2][1] + sPart[3][1];
        out[ray * 3 + 2] = sPart[0][2] + sPart[1][2] + sPart[2][2] + sPart[3][2];
    }
}

extern "C" void kernel_launch(void* const* d_in, const int* in_sizes, int n_in,
                              void* d_out, int out_size, void* d_ws, size_t ws_size,
                              hipStream_t stream) {
    const int n_rays = in_sizes[0] / 3;   // 4096
    nerf_mfma<<<n_rays, 256, 0, stream>>>(
        (const float*)d_in[0],  (const float*)d_in[1],  (const float*)d_in[2],
        (const float*)d_in[3],  (const float*)d_in[4],  (const float*)d_in[5],
        (const float*)d_in[6],  (const float*)d_in[7],  (const float*)d_in[8],
        (const float*)d_in[9],  (const float*)d_in[10], (const float*)d_in[11],
        (const float*)d_in[12], (float*)d_out);
}

// Round 4
// 241.626 us; speedup vs baseline: 2.2449x; 1.0537x over previous
//
#include <hip/hip_runtime.h>
#include <math.h>
#include <stdint.h>

#define S    256
#define GN   128

typedef __attribute__((ext_vector_type(8))) short  short8;   // 8 bf16
typedef __attribute__((ext_vector_type(4))) float  floatx4;  // MFMA C/D

// workspace layout (bytes)
#define WS_BHI 0          // ushort[4*5*64*8]  = 20480 B
#define WS_BLO 20480      // ushort[4*5*64*8]  = 20480 B
#define WS_RW1 40960      // ushort[2*4*64*8]  =  8192 B
#define WS_B2S 49152      // float

__device__ __forceinline__ unsigned short bf16_rtne(float f) {
    uint32_t u = __builtin_bit_cast(uint32_t, f);
    uint32_t r = (u + 0x7fffu + ((u >> 16) & 1u)) >> 16;
    return (unsigned short)r;
}
__device__ __forceinline__ unsigned short bf16_rhu(float f) {   // round-half-up, 2 ops
    return (unsigned short)((__builtin_bit_cast(uint32_t, f) + 0x8000u) >> 16);
}
__device__ __forceinline__ float bf16_to_f(unsigned short s) {
    uint32_t u = ((uint32_t)s) << 16;
    return __builtin_bit_cast(float, u);
}

// ---------- pre-pack kernel: weights -> bf16 hi/lo in MFMA fragment order ----
__global__ __launch_bounds__(256)
void nerf_prep(const float* __restrict__ f_w2, const float* __restrict__ f_b2,
               const float* __restrict__ s_w,  const float* __restrict__ s_b,
               const float* __restrict__ r_w1, unsigned char* __restrict__ ws)
{
    __shared__ float ws2[128];
    const int tid = threadIdx.x;
    if (tid < 128) {                       // ws2 = W2 @ s_w  (fp32)
        float acc = 0.0f;
        for (int n = 0; n < 64; ++n) acc += f_w2[tid * 64 + n] * s_w[n];
        ws2[tid] = acc;
    } else if (tid == 128) {               // b2s = b2 . s_w + s_b
        float acc = s_b[0];
        for (int n = 0; n < 64; ++n) acc += f_b2[n] * s_w[n];
        *(float*)(ws + WS_B2S) = acc;
    }
    __syncthreads();

    unsigned short* bhi = (unsigned short*)(ws + WS_BHI);
    unsigned short* blo = (unsigned short*)(ws + WS_BLO);
    for (int i = tid; i < 10240; i += 256) {
        int j = i & 7, L = (i >> 3) & 63, g = i >> 9;   // g = kc*5 + tn
        int tn = g % 5, kc = g / 5;
        int q = L >> 4, cc = L & 15;
        int k = kc * 32 + q * 8 + j;
        float val = (tn < 4) ? f_w2[k * 64 + tn * 16 + cc]
                             : ((cc == 0) ? ws2[k] : 0.0f);
        unsigned short hi = bf16_rtne(val);
        bhi[i] = hi;
        blo[i] = bf16_rtne(val - bf16_to_f(hi));
    }
    unsigned short* rw = (unsigned short*)(ws + WS_RW1);
    for (int i = tid; i < 4096; i += 256) {
        int j = i & 7, L = (i >> 3) & 63, g = i >> 9;   // g = ks*4 + tn
        int tn = g & 3, ks = g >> 2;
        int q = L >> 4, cc = L & 15;
        int k = ks * 32 + q * 8 + j;
        rw[i] = bf16_rtne(r_w1[k * 64 + tn * 16 + cc]);
    }
}

// ---------------------------- main kernel -----------------------------------
__global__ __launch_bounds__(256, 3)
void nerf_mfma(const float* __restrict__ rays_o,
               const float* __restrict__ rays_d,
               const float* __restrict__ grid,
               const float* __restrict__ f_w1,
               const float* __restrict__ f_b1,
               const float* __restrict__ f_b2,
               const float* __restrict__ r_w1,
               const float* __restrict__ r_b1,
               const float* __restrict__ r_w2,
               const float* __restrict__ r_b2,
               const unsigned char* __restrict__ ws,
               float* __restrict__ out)
{
    // fh: bf16 [256 rows][64], XOR-swizzled in 8-ushort groups: conflict-free b128
    __shared__ unsigned short fh[256 * 64];
    __shared__ float aLds[S];
    __shared__ float maskLds[S];
    __shared__ float distLds[S];
    __shared__ float sWaveSum[4];
    __shared__ float sPart[4][3];

    const int tid   = threadIdx.x;
    const int ray   = blockIdx.x;
    const int lane  = tid & 63;
    const int wv    = tid >> 6;
    const int q     = lane >> 4;
    const int c     = lane & 15;
    const int mbase = wv * 64;

    // ---------------- Phase A: geometry + grid sample (thread = sample) ------
    const float stop = 1.0f - 1.0f / (float)(S + 2);
    const float step = stop / (float)S;
    float u0 = (float)tid * step;
    float u1 = (float)(tid + 1) * step;
    float t    = (u0 < 0.5f) ? 2.0f * u0 : 1.0f / (2.0f - 2.0f * u0);
    float tn_  = (u1 < 0.5f) ? 2.0f * u1 : 1.0f / (2.0f - 2.0f * u1);
    float dist = tn_ - t;

    float ox = rays_o[ray * 3 + 0], oy = rays_o[ray * 3 + 1], oz = rays_o[ray * 3 + 2];
    float dxv = rays_d[ray * 3 + 0], dyv = rays_d[ray * 3 + 1], dzv = rays_d[ray * 3 + 2];

    float px = ox + dxv * t, py = oy + dyv * t, pz = oz + dzv * t;
    float nrm = sqrtf(px * px + py * py + pz * pz);
    float scale = (nrm <= 1.0f) ? 0.5f : (2.0f - 1.0f / nrm) / nrm * 0.5f;
    float cx = px * scale, cy = py * scale, cz = pz * scale;

    float ix = ((cx + 1.0f) * (float)GN - 1.0f) * 0.5f;
    float iy = ((cy + 1.0f) * (float)GN - 1.0f) * 0.5f;
    float iz = ((cz + 1.0f) * (float)GN - 1.0f) * 0.5f;
    float fx0 = floorf(ix), fy0 = floorf(iy), fz0 = floorf(iz);
    float fx = ix - fx0, fy = iy - fy0, fz = iz - fz0;
    int x0 = (int)fx0, y0 = (int)fy0, z0 = (int)fz0;

    float occ = 0.0f;
    #pragma unroll
    for (int dzc = 0; dzc < 2; ++dzc)
    #pragma unroll
    for (int dyc = 0; dyc < 2; ++dyc)
    #pragma unroll
    for (int dxc = 0; dxc < 2; ++dxc) {
        int xc = x0 + dxc, yc = y0 + dyc, zc = z0 + dzc;
        float w = (dxc ? fx : 1.0f - fx) * (dyc ? fy : 1.0f - fy) * (dzc ? fz : 1.0f - fz);
        if (xc >= 0 && xc < GN && yc >= 0 && yc < GN && zc >= 0 && zc < GN)
            occ += w * grid[(zc * GN + yc) * GN + xc];
    }
    bool maskA = occ > 0.01f;
    maskLds[tid] = maskA ? 1.0f : 0.0f;
    distLds[tid] = dist;

    // coords of the A-fragment rows this thread covers (intra-wave broadcast)
    float cxs[4], cys[4], czs[4];
    #pragma unroll
    for (int tm = 0; tm < 4; ++tm) {
        int src = tm * 16 + c;
        cxs[tm] = __shfl(cx, src, 64);
        cys[tm] = __shfl(cy, src, 64);
        czs[tm] = __shfl(cz, src, 64);
    }

    // ---------------- Phase B: feat GEMM + sigma column, no LDS, no barriers -
    floatx4 facc[4][4];
    floatx4 sacc[4];
    {
        float b2v[4];
        #pragma unroll
        for (int tn = 0; tn < 4; ++tn) b2v[tn] = f_b2[tn * 16 + c];
        #pragma unroll
        for (int tm = 0; tm < 4; ++tm) {
            #pragma unroll
            for (int tn = 0; tn < 4; ++tn) {
                floatx4 v; v[0] = b2v[tn]; v[1] = b2v[tn]; v[2] = b2v[tn]; v[3] = b2v[tn];
                facc[tm][tn] = v;
            }
            floatx4 z; z[0] = 0.0f; z[1] = 0.0f; z[2] = 0.0f; z[3] = 0.0f;
            sacc[tm] = z;
        }
    }

    const unsigned short* __restrict__ bhiP = (const unsigned short*)(ws + WS_BHI);
    const unsigned short* __restrict__ bloP = (const unsigned short*)(ws + WS_BLO);

    #pragma unroll 1
    for (int kc = 0; kc < 4; ++kc) {
        const int k0 = kc * 32 + q * 8;
        float w1x[8], w1y[8], w1z[8], b1v[8];
        *(float4*)(w1x)     = *(const float4*)(f_w1 + k0);
        *(float4*)(w1x + 4) = *(const float4*)(f_w1 + k0 + 4);
        *(float4*)(w1y)     = *(const float4*)(f_w1 + 128 + k0);
        *(float4*)(w1y + 4) = *(const float4*)(f_w1 + 128 + k0 + 4);
        *(float4*)(w1z)     = *(const float4*)(f_w1 + 256 + k0);
        *(float4*)(w1z + 4) = *(const float4*)(f_w1 + 256 + k0 + 4);
        *(float4*)(b1v)     = *(const float4*)(f_b1 + k0);
        *(float4*)(b1v + 4) = *(const float4*)(f_b1 + k0 + 4);

        // A fragments: layer-1 recomputed in-register, hi=trunc, lo=rhu
        short8 Ah[4], Al[4];
        #pragma unroll
        for (int tm = 0; tm < 4; ++tm) {
            #pragma unroll
            for (int j = 0; j < 8; ++j) {
                float h = b1v[j] + cxs[tm] * w1x[j] + cys[tm] * w1y[j] + czs[tm] * w1z[j];
                h = fmaxf(h, 0.0f);
                uint32_t u = __builtin_bit_cast(uint32_t, h);
                float hf = __builtin_bit_cast(float, u & 0xffff0000u);
                Ah[tm][j] = (short)(u >> 16);
                Al[tm][j] = (short)bf16_rhu(h - hf);
            }
        }
        // B fragments: straight dwordx4 loads, zero conversion
        const int bbase = (kc * 5) * 512 + lane * 8;
        #pragma unroll
        for (int tn = 0; tn < 5; ++tn) {
            short8 bh = *(const short8*)(bhiP + bbase + tn * 512);
            short8 bl = *(const short8*)(bloP + bbase + tn * 512);
            #pragma unroll
            for (int tm = 0; tm < 4; ++tm) {
                floatx4 acc = (tn < 4) ? facc[tm][tn] : sacc[tm];
                acc = __builtin_amdgcn_mfma_f32_16x16x32_bf16(Ah[tm], bh, acc, 0, 0, 0);
                acc = __builtin_amdgcn_mfma_f32_16x16x32_bf16(Al[tm], bh, acc, 0, 0, 0);
                acc = __builtin_amdgcn_mfma_f32_16x16x32_bf16(Ah[tm], bl, acc, 0, 0, 0);
                if (tn < 4) facc[tm][tn] = acc; else sacc[tm] = acc;
            }
        }
    }

    // ---------------- Phase C: feat -> fh (swizzled bf16); sigma -> aLds -----
    #pragma unroll
    for (int tm = 0; tm < 4; ++tm)
        #pragma unroll
        for (int tn = 0; tn < 4; ++tn)
            #pragma unroll
            for (int reg = 0; reg < 4; ++reg) {
                int m = mbase + tm * 16 + q * 4 + reg;
                int n = tn * 16 + c;
                int idx = m * 64 + (((n >> 3) ^ (m & 7)) << 3) + (n & 7);
                fh[idx] = bf16_rhu(facc[tm][tn][reg]);
            }

    {
        float b2s = *(const float*)(ws + WS_B2S);
        if (c == 0) {
            #pragma unroll
            for (int tm = 0; tm < 4; ++tm)
                #pragma unroll
                for (int reg = 0; reg < 4; ++reg) {
                    int m = mbase + tm * 16 + q * 4 + reg;
                    float sa = sacc[tm][reg] + b2s;
                    float sg = (maskLds[m] > 0.5f)
                             ? (fmaxf(sa, 0.0f) + __logf(1.0f + __expf(-fabsf(sa)))) : 0.0f;
                    aLds[m] = -sg * distLds[m];
                }
        }
    }
    __builtin_amdgcn_wave_barrier();

    // ---------------- transmittance scan -------------------------------------
    float av = aLds[tid];
    float v = av;
    #pragma unroll
    for (int off = 1; off < 64; off <<= 1) {
        float u2 = __shfl_up(v, off);
        if (lane >= off) v += u2;
    }
    if (lane == 63) sWaveSum[wv] = v;
    __syncthreads();
    float basev = 0.0f;
    #pragma unroll
    for (int w = 0; w < 4; ++w) basev += (w < wv) ? sWaveSum[w] : 0.0f;
    float excl = __shfl_up(v, 1);
    if (lane == 0) excl = 0.0f;
    float cum    = basev + excl;
    float trans  = __expf(cum);
    float weight = trans * (1.0f - __expf(av));
    bool  mask2  = maskA && (trans > 1e-4f);

    // ---------------- Phase D: rgb-hidden GEMM -------------------------------
    float hd[4];
    #pragma unroll
    for (int tn = 0; tn < 4; ++tn) {
        int n = tn * 16 + c;
        hd[tn] = r_b1[n] + dxv * r_w1[64 * 64 + n] + dyv * r_w1[65 * 64 + n] + dzv * r_w1[66 * 64 + n];
    }

    short8 afr[4][2];
    #pragma unroll
    for (int tm = 0; tm < 4; ++tm)
        #pragma unroll
        for (int ks = 0; ks < 2; ++ks) {
            int m = mbase + tm * 16 + c;
            int gl = ks * 4 + q;
            afr[tm][ks] = *(const short8*)&fh[m * 64 + ((gl ^ (m & 7)) << 3)];
        }

    floatx4 hacc[4][4];
    #pragma unroll
    for (int tm = 0; tm < 4; ++tm)
        #pragma unroll
        for (int tn = 0; tn < 4; ++tn) {
            floatx4 z; z[0] = 0.0f; z[1] = 0.0f; z[2] = 0.0f; z[3] = 0.0f;
            hacc[tm][tn] = z;
        }
    const unsigned short* __restrict__ rwP = (const unsigned short*)(ws + WS_RW1);
    #pragma unroll
    for (int ks = 0; ks < 2; ++ks)
        #pragma unroll
        for (int tn = 0; tn < 4; ++tn) {
            short8 rb = *(const short8*)(rwP + ((ks * 4 + tn) * 64 + lane) * 8);
            #pragma unroll
            for (int tm = 0; tm < 4; ++tm)
                hacc[tm][tn] = __builtin_amdgcn_mfma_f32_16x16x32_bf16(afr[tm][ks], rb, hacc[tm][tn], 0, 0, 0);
        }

    __builtin_amdgcn_wave_barrier();
    #pragma unroll
    for (int tm = 0; tm < 4; ++tm)
        #pragma unroll
        for (int tn = 0; tn < 4; ++tn)
            #pragma unroll
            for (int reg = 0; reg < 4; ++reg) {
                int m = mbase + tm * 16 + q * 4 + reg;
                int n = tn * 16 + c;
                float hv = fmaxf(hacc[tm][tn][reg] + hd[tn], 0.0f);
                int idx = m * 64 + (((n >> 3) ^ (m & 7)) << 3) + (n & 7);
                fh[idx] = bf16_rhu(hv);
            }
    __builtin_amdgcn_wave_barrier();

    // ---------------- Phase E: final 64->3 (thread = sample) -----------------
    float o0 = r_b2[0], o1 = r_b2[1], o2 = r_b2[2];
    const uint32_t* __restrict__ fr = (const uint32_t*)fh;
    #pragma unroll
    for (int gl = 0; gl < 8; ++gl) {
        int pg = gl ^ (tid & 7);
        uint4 pk = *(const uint4*)(fr + tid * 32 + pg * 4);
        uint32_t pw[4] = {pk.x, pk.y, pk.z, pk.w};
        #pragma unroll
        for (int tt = 0; tt < 4; ++tt) {
            float h0 = __builtin_bit_cast(float, pw[tt] << 16);
            float h1 = __builtin_bit_cast(float, pw[tt] & 0xffff0000u);
            int k = gl * 8 + 2 * tt;
            o0 += h0 * r_w2[k * 3 + 0] + h1 * r_w2[k * 3 + 3];
            o1 += h0 * r_w2[k * 3 + 1] + h1 * r_w2[k * 3 + 4];
            o2 += h0 * r_w2[k * 3 + 2] + h1 * r_w2[k * 3 + 5];
        }
    }
    float r = 0.0f, g = 0.0f, b = 0.0f;
    if (mask2) {
        r = weight / (1.0f + __expf(-o0));
        g = weight / (1.0f + __expf(-o1));
        b = weight / (1.0f + __expf(-o2));
    }

    #pragma unroll
    for (int off = 32; off > 0; off >>= 1) {
        r += __shfl_down(r, off);
        g += __shfl_down(g, off);
        b += __shfl_down(b, off);
    }
    if (lane == 0) { sPart[wv][0] = r; sPart[wv][1] = g; sPart[wv][2] = b; }
    __syncthreads();
    if (tid == 0) {
        out[ray * 3 + 0] = sPart[0][0] + sPart[1][0] + sPart[2][0] + sPart[3][0];
        out[ray * 3 + 1] = sPart[0][1] + sPart[1][1] + sPart[2][1] + sPart[3][1];
        out[ray * 3 + 2] = sPart[0][2] + sPart[1][2] + sPart[2][2] + sPart[3][2];
    }
}

extern "C" void kernel_launch(void* const* d_in, const int* in_sizes, int n_in,
                              void* d_out, int out_size, void* d_ws, size_t ws_size,
                              hipStream_t stream) {
    const int n_rays = in_sizes[0] / 3;   // 4096
    nerf_prep<<<1, 256, 0, stream>>>(
        (const float*)d_in[5], (const float*)d_in[6], (const float*)d_in[7],
        (const float*)d_in[8], (const float*)d_in[9], (unsigned char*)d_ws);
    nerf_mfma<<<n_rays, 256, 0, stream>>>(
        (const float*)d_in[0],  (const float*)d_in[1],  (const float*)d_in[2],
        (const float*)d_in[3],  (const float*)d_in[4],  (const float*)d_in[6],
        (const float*)d_in[9],  (const float*)d_in[10], (const float*)d_in[11],
        (const float*)d_in[12], (const unsigned char*)d_ws, (float*)d_out);
}